// Round 9
// baseline (279.711 us; speedup 1.0000x reference)
//
#include <hip/hip_runtime.h>

typedef __attribute__((ext_vector_type(8))) short short8;
typedef __attribute__((ext_vector_type(4))) float f32x4;

#define XP_ELEMS (32u * 66u * 66u * 128u)  /* 17,842,176 bf16 elements */
#define WT_ELEMS (256u * 1152u)            /* 294,912 bf16 elements */
#define WS_NEED  ((size_t)(XP_ELEMS + WT_ELEMS) * 2u)

typedef const __attribute__((address_space(1))) void* gp1_t;
typedef __attribute__((address_space(3))) void* lp3_t;
typedef const __attribute__((address_space(1))) short8* g8p_t;

__device__ __forceinline__ void gload16(const void* g, void* l) {
  __builtin_amdgcn_global_load_lds((gp1_t)g, (lp3_t)l, 16, 0, 0);
}

__device__ __forceinline__ short f2bf(float f) {
  unsigned u = __float_as_uint(f);
  u = (u + 0x7FFFu + ((u >> 16) & 1u)) >> 16;  // RNE truncate to bf16
  return (short)u;
}

// Transpose one (b, y) plane: x[b][cin][y][px] fp32 -> x_p[b][y+1][px+1][cin] bf16.
__global__ __launch_bounds__(256) void prepass_x(const float* __restrict__ x,
                                                 short* __restrict__ xp) {
  __shared__ short lds[64 * 128];  // [px][cin, granule-swizzled], 16 KB
  const int y = blockIdx.x;   // 0..63
  const int b = blockIdx.y;   // 0..31
  const int t = threadIdx.x;

  const float* src = x + (long)b * 128 * 4096 + y * 64;
#pragma unroll
  for (int i = 0; i < 8; ++i) {
    int f4 = t + i * 256;          // 0..2047
    int cin = f4 >> 4, px4 = f4 & 15;
    float4 v = *(const float4*)(src + (long)cin * 4096 + px4 * 4);
    float vv[4] = {v.x, v.y, v.z, v.w};
#pragma unroll
    for (int j = 0; j < 4; ++j) {
      int px = px4 * 4 + j;
      int g = (cin >> 3) ^ ((px ^ (px >> 2)) & 15);
      lds[px * 128 + (g << 3) + (cin & 7)] = f2bf(vv[j]);
    }
  }
  __syncthreads();
  short* dst = xp + ((long)(b * 66 + y + 1) * 66 + 1) * 128;
#pragma unroll
  for (int i = 0; i < 4; ++i) {
    int f8 = t + i * 256;          // 0..1023
    int px = f8 >> 4, c8 = f8 & 15;
    int g = c8 ^ ((px ^ (px >> 2)) & 15);
    short8 v = *(const short8*)&lds[px * 128 + (g << 3)];
    *(short8*)(dst + (long)px * 128 + c8 * 8) = v;
  }
  short8 z = (short8)0;
  short* rowbase = xp + (long)(b * 66 + y + 1) * 66 * 128;
  if (t < 32) {
    int px = (t < 16) ? 0 : 65;
    int c8 = t & 15;
    *(short8*)(rowbase + (long)px * 128 + c8 * 8) = z;
  }
  if (y == 0) {
    short* r0 = xp + (long)(b * 66) * 66 * 128;
    for (int idx = t; idx < 66 * 16; idx += 256) *(short8*)(r0 + idx * 8) = z;
  }
  if (y == 63) {
    short* r65 = xp + ((long)(b * 66) + 65) * 66 * 128;
    for (int idx = t; idx < 66 * 16; idx += 256) *(short8*)(r65 + idx * 8) = z;
  }
}

// weight[cout][cin][kh][kw] fp32 -> wt2 in MFMA-FRAGMENT layout:
//   idx = ((mb*36 + c32) << 9) + l15*32 + q*8 + k7
//   where cout = mb*16 + l15, k = (kh*3+kw)*128 + cin = c32*32 + q*8 + k7.
//   One (mb, c32) block = 1 KB = exactly one wave's coalesced af[i][c]
//   global_load_dwordx4 footprint (lane l = q*16+l15 reads 16B at
//   l15*64 + q*16 bytes).  Lets conv_gemm read A global->reg, no LDS.
__global__ __launch_bounds__(256) void prepass_w(const float* __restrict__ w,
                                                 short* __restrict__ wt) {
  int o    = blockIdx.x * 256 + threadIdx.x;  // < 294912 exactly
  int cout = o / 1152;
  int r    = o % 1152;
  int kh   = r / 384;
  int kw   = (r / 128) % 3;
  int cin  = r & 127;
  int mb = cout >> 4, l15 = cout & 15;
  int c32 = r >> 5, q = (r >> 3) & 3, k7 = r & 7;
  wt[((mb * 36 + c32) << 9) + (l15 << 5) + (q << 3) + k7] =
      f2bf(w[((cout * 128 + cin) * 3 + kh) * 3 + kw]);
}

// Implicit-GEMM conv, A-direct-global + B-LDS design.
//   Measured basis (r0-r8): every LDS-staged schedule pinned at 27-35%
//   MfmaUtil because per K-tile LDS traffic (192KB rd + 64KB wr ~ 2800 cyc)
//   >= MFMA (2483 cyc) -> serialization caps utilization.  Fix: A (weights,
//   576KB, L2-resident) is read DIRECTLY global->reg from the fragment-
//   shaped wt2 layout (1KB coalesced per wave-load), eliminating A's LDS
//   writes AND reads.  LDS per tile drops 256KB -> 96KB (~1130 cyc) ->
//   MFMA is now the dominant pipe.
//   Pipeline per K-tile T (4 quadrant phases, 1 barrier/tile):
//     (0,0): ALOAD afB=A(T,mq1) [8 vm]; BREAD nq0; LGK0; MM(afA,mq0,nq0)
//     (0,1): BREAD nq1; BSTAGE B(T+1) [4 gload_lds]; LGK0; MM(afA,mq0,nq1)
//     (1,0): ALOAD afA=A(T+1,mq0) [8 vm];            MM(afB,mq1,nq0)
//     (1,1): MM(afB,mq1,nq1); VMC(8); BAR()
//   A-loads are plain C++ derefs: compiler auto-inserts counted vmcnt
//   before first use (afA: vmcnt(8), afB: vmcnt(12)) -- 2-phase latency
//   cover.  Manual VMC(8) retires only the 4 B-stage loads (per-wave FIFO:
//   outstanding there = B[4] + afA(T+1)[8]), certifying B(T+1) block-wide
//   at the BAR; afA(T+1) stays in flight.  BREADs precede any BSTAGE in
//   program order so compiler alias-waits are non-draining.  B ring-2
//   (64KB): slot (T+1)&1 was last read at tile T-1, sealed by that tile's
//   BAR.  afA/afB have FIXED roles (no runtime reg indexing, rule #20).
__global__ __launch_bounds__(512, 2) void conv_gemm(const short* __restrict__ xp,
                                                    const short* __restrict__ wt,
                                                    float* __restrict__ out) {
  __shared__ alignas(16) short Blds[2 * 16384];  // ring-2 B, 64 KB
  const int tid = threadIdx.x;
  const int w   = tid >> 6;     // wave 0..7
  const int l   = tid & 63;
  const int l15 = l & 15;
  const int q   = l >> 4;
  const int wm2 = w >> 2;       // wave M half 0..1
  const int wn4 = w & 3;        // wave N quarter 0..3
  const int ntile = blockIdx.x; // 0..511

  // ---- B staging decomposition (verbatim r2/r7, verified)
  const int r6 = (tid >> 2) & 63;
  const int cc = tid >> 8;
  const int pp = tid & 3;
  const int cs = pp ^ ((r6 >> 1) & 3);              // source k-granule (swizzle)
  const int ldsB0 = cc * 4096 + r6 * 32 + pp * 8 + ((r6 & 32) << 5);
  int bTh[2][2];                                    // [hb][nq] per-thread B src
#pragma unroll
  for (int hb = 0; hb < 2; ++hb)
#pragma unroll
    for (int nq = 0; nq < 2; ++nq) {
      int R  = (r6 & 31) + ((r6 >> 5) << 6) + nq * 32;  // LDS row within half
      int n  = (ntile << 8) + (hb << 7) + R;
      int bb = n >> 12, yy = (n >> 6) & 63, xx = n & 63;
      bTh[hb][nq] = ((bb * 66 + yy) * 66 + xx) * 128 + cc * 32 + cs * 8;
    }

  // ---- B frag read offsets (verbatim, conflict-free)
  int bRd[4];
#pragma unroll
  for (int nj = 0; nj < 4; ++nj) {
    int r = ((wn4 & 1) << 6) + (nj << 4) + l15;
    bRd[nj] = r * 32 + ((q ^ ((r >> 1) & 3)) << 3);
  }
  const int bHB = (wn4 >> 1) * 8192; // wave's B half base (within slot)

  // ---- A per-lane offset within each 1KB fragment block (shorts)
  const int aV = l15 * 32 + q * 8;

  f32x4 acc[8][4];
#pragma unroll
  for (int mi = 0; mi < 8; ++mi)
#pragma unroll
    for (int nj = 0; nj < 4; ++nj) acc[mi][nj] = (f32x4)0.f;

  short8 afA[4][2], afB[4][2], bf[4][2];

#define BAR()   do { __builtin_amdgcn_s_barrier(); \
                     asm volatile("" ::: "memory"); } while (0)
#define LGK0()  asm volatile("s_waitcnt lgkmcnt(0)" ::: "memory")
#define VMC(n)  asm volatile("s_waitcnt vmcnt(" #n ")" ::: "memory")

  // A(T, mq) fragment loads: 8 coalesced 1KB global_load_dwordx4 from wt2.
  auto ALOAD = [&](int T, int mq, short8 (&d)[4][2]) {
    const int mb0 = wm2 * 8 + mq * 4;
#pragma unroll
    for (int i = 0; i < 4; ++i)
#pragma unroll
      for (int c = 0; c < 2; ++c)
        d[i][c] = *(g8p_t)(wt + (((long)((mb0 + i) * 36 + 2 * T + c) << 9) + aV));
  };
  auto ST_B = [&](int s, int nq, int sh) {
    gload16(xp + sh + bTh[0][nq], &Blds[s * 16384 + (nq << 10) + ldsB0]);
    gload16(xp + sh + bTh[1][nq], &Blds[s * 16384 + 8192 + (nq << 10) + ldsB0]);
  };
  auto BSTAGE = [&](int T) {     // stage B(T) into slot T&1 (4 gload_lds)
    const int J = T >> 1, h = T & 1;
    const int kh = J / 3, kw = J - kh * 3;
    const int sh = (kh * 66 + kw) * 128 + h * 64;
    ST_B(T & 1, 0, sh);
    ST_B(T & 1, 1, sh);
  };
  auto BREAD = [&](int s, int nq) {
#pragma unroll
    for (int j = 0; j < 2; ++j)
#pragma unroll
      for (int c = 0; c < 2; ++c)
        bf[nq * 2 + j][c] =
            *(const short8*)&Blds[s * 16384 + bHB + c * 4096 + bRd[nq * 2 + j]];
  };
  auto MM = [&](short8 (&a)[4][2], int mq, int nq) {
    __builtin_amdgcn_s_setprio(1);
#pragma unroll
    for (int c = 0; c < 2; ++c)
#pragma unroll
      for (int i = 0; i < 4; ++i)
#pragma unroll
        for (int j = 0; j < 2; ++j)
          acc[mq * 4 + i][nq * 2 + j] = __builtin_amdgcn_mfma_f32_16x16x32_bf16(
              a[i][c], bf[nq * 2 + j][c], acc[mq * 4 + i][nq * 2 + j], 0, 0, 0);
    __builtin_amdgcn_s_setprio(0);
  };

  // ---- prologue: stage B(0); load A(0,mq0); certify B(0) (afA stays in flight)
  BSTAGE(0);           // 4 vm
  ALOAD(0, 0, afA);    // 8 vm
  VMC(8);              // retires B(0); outstanding {afA(0)}=8
  BAR();

  // ---- steady: tiles 0..16 (each stages B(T+1), loads A(T+1,mq0))
#pragma unroll 1
  for (int T = 0; T < 17; ++T) {
    const int s = T & 1;
    // (0,0)
    ALOAD(T, 1, afB);
    BREAD(s, 0);
    LGK0();
    MM(afA, 0, 0);
    // (0,1)
    BREAD(s, 1);
    BSTAGE(T + 1);
    LGK0();
    MM(afA, 0, 1);
    // (1,0)
    ALOAD(T + 1, 0, afA);
    MM(afB, 1, 0);
    // (1,1)
    MM(afB, 1, 1);
    VMC(8);   // retires the 4 B-stage loads -> B(T+1) certified at BAR
    BAR();
  }

  // ---- peel T=17 (no staging; B(17) certified at T=16's fence)
  ALOAD(17, 1, afB);
  BREAD(1, 0);
  LGK0();
  MM(afA, 0, 0);
  BREAD(1, 1);
  LGK0();
  MM(afA, 0, 1);
  MM(afB, 1, 0);
  MM(afB, 1, 1);

  // ---- epilogue: C/D layout col=lane&15, row=quad*4+reg (m89/m91-verified)
  const int bimg = ntile >> 4;
  const int yx0  = ((ntile & 15) << 8) + (wn4 << 6) + l15;
  float* outb = out + (long)bimg * (256 * 4096) + yx0;
#pragma unroll
  for (int mi = 0; mi < 8; ++mi) {
#pragma unroll
    for (int r = 0; r < 4; ++r) {
      const int cout = (wm2 << 7) + (mi << 4) + (q << 2) + r;
      float* orow = outb + (long)cout * 4096;
#pragma unroll
      for (int nj = 0; nj < 4; ++nj) orow[nj << 4] = acc[mi][nj][r];
    }
  }
#undef BAR
#undef LGK0
#undef VMC
}

// Correctness fallback if workspace is too small (slow, fp32 direct conv).
__global__ __launch_bounds__(256) void naive_conv(const float* __restrict__ x,
                                                  const float* __restrict__ wgt,
                                                  float* __restrict__ out) {
  long o = (long)blockIdx.x * 256 + threadIdx.x;
  int xx = (int)(o & 63);
  int y  = (int)((o >> 6) & 63);
  int co = (int)((o >> 12) & 255);
  int b  = (int)(o >> 20);
  float s = 0.f;
  for (int ci = 0; ci < 128; ++ci) {
    for (int kh = 0; kh < 3; ++kh) {
      int iy = y + kh - 1;
      if (iy < 0 || iy > 63) continue;
      for (int kw = 0; kw < 3; ++kw) {
        int ix = xx + kw - 1;
        if (ix < 0 || ix > 63) continue;
        s += x[((long)(b * 128 + ci) * 64 + iy) * 64 + ix] *
             wgt[((co * 128 + ci) * 3 + kh) * 3 + kw];
      }
    }
  }
  out[o] = s;
}

extern "C" void kernel_launch(void* const* d_in, const int* in_sizes, int n_in,
                              void* d_out, int out_size, void* d_ws, size_t ws_size,
                              hipStream_t stream) {
  (void)in_sizes; (void)n_in;
  const float* x   = (const float*)d_in[0];
  const float* wgt = (const float*)d_in[1];
  float* out = (float*)d_out;
  if (ws_size >= WS_NEED) {
    short* xp = (short*)d_ws;
    short* wt = xp + XP_ELEMS;
    prepass_x<<<dim3(64, 32), dim3(256), 0, stream>>>(x, xp);
    prepass_w<<<dim3(WT_ELEMS / 256), dim3(256), 0, stream>>>(wgt, wt);
    conv_gemm<<<dim3(512), dim3(512), 0, stream>>>(xp, wt, out);
  } else {
    naive_conv<<<dim3(out_size / 256), dim3(256), 0, stream>>>(x, wgt, out);
  }
}